// Round 1
// baseline (1185.650 us; speedup 1.0000x reference)
//
#include <hip/hip_runtime.h>
#include <hip/hip_bf16.h>
#include <cstdint>

// ---------------- CSR build ----------------

__global__ void hist_kernel(const int* __restrict__ dst, int* __restrict__ cnt, int E) {
    int e = blockIdx.x * blockDim.x + threadIdx.x;
    if (e < E) atomicAdd(&cnt[dst[e]], 1);
}

__global__ void scan_kernel(const int* __restrict__ cnt, int* __restrict__ rowptr, int n) {
    __shared__ int lds[256];
    __shared__ int carry;
    if (threadIdx.x == 0) { carry = 0; rowptr[0] = 0; }
    __syncthreads();
    for (int base = 0; base < n; base += 256) {
        int i = base + (int)threadIdx.x;
        int v = (i < n) ? cnt[i] : 0;
        lds[threadIdx.x] = v;
        __syncthreads();
        for (int off = 1; off < 256; off <<= 1) {
            int t = (threadIdx.x >= (unsigned)off) ? lds[threadIdx.x - off] : 0;
            __syncthreads();
            lds[threadIdx.x] += t;
            __syncthreads();
        }
        int incl = lds[threadIdx.x];
        int tot  = lds[255];
        int c = carry;
        if (i < n) rowptr[i + 1] = c + incl;
        __syncthreads();
        if (threadIdx.x == 0) carry = c + tot;
        __syncthreads();
    }
}

__global__ void scatter_kernel(const int* __restrict__ src, const int* __restrict__ dst,
                               const int* __restrict__ rowptr, int* __restrict__ cnt,
                               int* __restrict__ src_sorted, int E) {
    int e = blockIdx.x * blockDim.x + threadIdx.x;
    if (e < E) {
        int d = dst[e];
        int p = rowptr[d] + atomicAdd(&cnt[d], 1);
        src_sorted[p] = src[e];
    }
}

// ---------------- GEMM: out[n, j] = sum_k X[n,k]*W[k,j] + b[j] ----------------
// Block: 256 threads, computes a 64(row) x 64(col) tile; per-thread 4x4.

template <int K>
__global__ __launch_bounds__(256) void gemm_bias_kernel(
    const float* __restrict__ X, const float* __restrict__ W,
    const float* __restrict__ bias, float* __restrict__ out,
    int nrows, int ncols) {
    // LDS budget: K=128 -> exactly 64KB (no padding); K=64 -> padded.
    constexpr int XP = (K == 128) ? 128 : (K + 1);
    constexpr int WP = (K == 128) ? 64  : 65;
    __shared__ float xs[64 * XP];
    __shared__ float ws[K * WP];

    int row0 = blockIdx.x * 64, col0 = blockIdx.y * 64;
    int tid = threadIdx.x;

    for (int idx = tid; idx < 64 * K; idx += 256) {
        int r = idx / K, c = idx % K;   // K is pow2 -> shifts
        int gr = row0 + r;
        xs[r * XP + c] = (gr < nrows) ? X[(size_t)gr * K + c] : 0.f;
    }
    for (int idx = tid; idx < K * 64; idx += 256) {
        int r = idx >> 6, c = idx & 63;
        ws[r * WP + c] = W[r * ncols + col0 + c];
    }
    __syncthreads();

    int tc = (tid & 15) * 4;
    int tr = (tid >> 4) * 4;
    float acc[4][4] = {};
    for (int k = 0; k < K; ++k) {
        float a[4], b[4];
        #pragma unroll
        for (int r = 0; r < 4; ++r) a[r] = xs[(tr + r) * XP + k];
        #pragma unroll
        for (int c = 0; c < 4; ++c) b[c] = ws[k * WP + tc + c];
        #pragma unroll
        for (int r = 0; r < 4; ++r)
            #pragma unroll
            for (int c = 0; c < 4; ++c) acc[r][c] += a[r] * b[c];
    }

    #pragma unroll
    for (int r = 0; r < 4; ++r) {
        int gr = row0 + tr + r;
        if (gr < nrows) {
            #pragma unroll
            for (int c = 0; c < 4; ++c)
                out[(size_t)gr * ncols + col0 + tc + c] = acc[r][c] + bias[col0 + tc + c];
        }
    }
}

// ---------------- Fused per-node online-softmax attention ----------------
// One wave (64 lanes) per destination node; lane = channel c in [0,64).
// H=2 heads held as paired registers.

__global__ __launch_bounds__(256) void attn_kernel(
    const float* __restrict__ Q, const float* __restrict__ Kb,
    const float* __restrict__ V, const float* __restrict__ S,
    const int* __restrict__ rowptr, const int* __restrict__ src_sorted,
    float* __restrict__ out, int n) {
    int wave = blockIdx.x * 4 + (threadIdx.x >> 6);
    int lane = threadIdx.x & 63;
    if (wave >= n) return;
    int node = wave;

    float q0 = Q[(size_t)node * 128 + lane];
    float q1 = Q[(size_t)node * 128 + 64 + lane];
    float m0 = -__builtin_inff(), m1 = -__builtin_inff();
    float s0 = 0.f, s1 = 0.f, a0 = 0.f, a1 = 0.f;

    int beg = rowptr[node], end = rowptr[node + 1];
    for (int i = beg; i < end; ++i) {
        int src = src_sorted[i];
        const float* kp = Kb + (size_t)src * 128;
        const float* vp = V + (size_t)src * 128;
        float k0 = kp[lane], k1 = kp[64 + lane];
        float v0 = vp[lane], v1 = vp[64 + lane];
        float d0 = q0 * k0, d1 = q1 * k1;
        #pragma unroll
        for (int off = 32; off >= 1; off >>= 1) {
            d0 += __shfl_xor(d0, off);
            d1 += __shfl_xor(d1, off);
        }
        d0 *= 0.125f;  // 1/sqrt(64)
        d1 *= 0.125f;
        float nm0 = fmaxf(m0, d0), nm1 = fmaxf(m1, d1);
        float f0 = __expf(m0 - nm0), f1 = __expf(m1 - nm1);
        float p0 = __expf(d0 - nm0), p1 = __expf(d1 - nm1);
        s0 = s0 * f0 + p0; a0 = a0 * f0 + p0 * v0; m0 = nm0;
        s1 = s1 * f1 + p1; a1 = a1 * f1 + p1 * v1; m1 = nm1;
    }

    float o = 0.5f * (a0 / (s0 + 1e-16f) + a1 / (s1 + 1e-16f));
    o += S[(size_t)node * 64 + lane];
    out[(size_t)node * 64 + lane] = fmaxf(o, 0.f);
}

// ---------------- launch ----------------

extern "C" void kernel_launch(void* const* d_in, const int* in_sizes, int n_in,
                              void* d_out, int out_size, void* d_ws, size_t ws_size,
                              hipStream_t stream) {
    const float* x = (const float*)d_in[0];
    const int* ei  = (const int*)d_in[1];
    const int N = in_sizes[0] / 128;
    const int E = in_sizes[1] / 2;
    const int* src = ei;
    const int* dst = ei + E;

    const float* Wq[3] = {(const float*)d_in[2],  (const float*)d_in[10], (const float*)d_in[18]};
    const float* bq[3] = {(const float*)d_in[3],  (const float*)d_in[11], (const float*)d_in[19]};
    const float* Wk[3] = {(const float*)d_in[4],  (const float*)d_in[12], (const float*)d_in[20]};
    const float* bk[3] = {(const float*)d_in[5],  (const float*)d_in[13], (const float*)d_in[21]};
    const float* Wv[3] = {(const float*)d_in[6],  (const float*)d_in[14], (const float*)d_in[22]};
    const float* bv[3] = {(const float*)d_in[7],  (const float*)d_in[15], (const float*)d_in[23]};
    const float* Wsk[3]= {(const float*)d_in[8],  (const float*)d_in[16], (const float*)d_in[24]};
    const float* bsk[3]= {(const float*)d_in[9],  (const float*)d_in[17], (const float*)d_in[25]};

    char* p = (char*)d_ws;
    int* rowptr = (int*)p; p += (size_t)(N + 1) * 4;
    int* cnt    = (int*)p; p += (size_t)N * 4;
    int* srcs   = (int*)p; p += (size_t)E * 4;
    p = (char*)(((uintptr_t)p + 255) & ~(uintptr_t)255);
    float* Qb = (float*)p; p += (size_t)N * 128 * 4;
    float* Kb = (float*)p; p += (size_t)N * 128 * 4;
    float* Vb = (float*)p; p += (size_t)N * 128 * 4;
    float* Sb = (float*)p; p += (size_t)N * 64 * 4;
    float* Hb = (float*)p; p += (size_t)N * 64 * 4;
    if ((size_t)(p - (char*)d_ws) > ws_size) return;  // workspace too small

    hipMemsetAsync(cnt, 0, (size_t)N * 4, stream);
    hist_kernel<<<(E + 255) / 256, 256, 0, stream>>>(dst, cnt, E);
    scan_kernel<<<1, 256, 0, stream>>>(cnt, rowptr, N);
    hipMemsetAsync(cnt, 0, (size_t)N * 4, stream);
    scatter_kernel<<<(E + 255) / 256, 256, 0, stream>>>(src, dst, rowptr, cnt, srcs, E);

    dim3 gq((N + 63) / 64, 2);   // 128-col outputs
    dim3 gs((N + 63) / 64, 1);   // 64-col output

    const float* X = x;
    for (int l = 0; l < 3; ++l) {
        if (l == 0) {
            gemm_bias_kernel<128><<<gq, 256, 0, stream>>>(X, Wq[l], bq[l], Qb, N, 128);
            gemm_bias_kernel<128><<<gq, 256, 0, stream>>>(X, Wk[l], bk[l], Kb, N, 128);
            gemm_bias_kernel<128><<<gq, 256, 0, stream>>>(X, Wv[l], bv[l], Vb, N, 128);
            gemm_bias_kernel<128><<<gs, 256, 0, stream>>>(X, Wsk[l], bsk[l], Sb, N, 64);
        } else {
            gemm_bias_kernel<64><<<gq, 256, 0, stream>>>(X, Wq[l], bq[l], Qb, N, 128);
            gemm_bias_kernel<64><<<gq, 256, 0, stream>>>(X, Wk[l], bk[l], Kb, N, 128);
            gemm_bias_kernel<64><<<gq, 256, 0, stream>>>(X, Wv[l], bv[l], Vb, N, 128);
            gemm_bias_kernel<64><<<gs, 256, 0, stream>>>(X, Wsk[l], bsk[l], Sb, N, 64);
        }
        float* outp = (l == 2) ? (float*)d_out : Hb;
        attn_kernel<<<(N + 3) / 4, 256, 0, stream>>>(Qb, Kb, Vb, Sb, rowptr, srcs, outp, N);
        X = Hb;
    }
}

// Round 2
// 985.347 us; speedup vs baseline: 1.2033x; 1.2033x over previous
//
#include <hip/hip_runtime.h>
#include <hip/hip_bf16.h>
#include <cstdint>

// ---------------- CSR build ----------------

__global__ void hist_kernel(const int* __restrict__ dst, int* __restrict__ cnt, int E) {
    int e = blockIdx.x * blockDim.x + threadIdx.x;
    if (e < E) atomicAdd(&cnt[dst[e]], 1);
}

// Per-block inclusive scan of 256 elements; writes rowptr[i+1] (pre-offset) and block partial.
__global__ __launch_bounds__(256) void block_scan_kernel(
    const int* __restrict__ cnt, int* __restrict__ rowptr,
    int* __restrict__ partials, int n) {
    __shared__ int lds[256];
    int tid = threadIdx.x;
    int i = blockIdx.x * 256 + tid;
    int v = (i < n) ? cnt[i] : 0;
    lds[tid] = v;
    __syncthreads();
    for (int off = 1; off < 256; off <<= 1) {
        int t = (tid >= off) ? lds[tid - off] : 0;
        __syncthreads();
        lds[tid] += t;
        __syncthreads();
    }
    if (i < n) rowptr[i + 1] = lds[tid];
    if (tid == 255) partials[blockIdx.x] = lds[255];
}

// Single block: exclusive scan of nb (<=256) partials in place.
__global__ __launch_bounds__(256) void partial_scan_kernel(int* __restrict__ partials, int nb) {
    __shared__ int lds[256];
    int tid = threadIdx.x;
    int v = (tid < nb) ? partials[tid] : 0;
    lds[tid] = v;
    __syncthreads();
    for (int off = 1; off < 256; off <<= 1) {
        int t = (tid >= off) ? lds[tid - off] : 0;
        __syncthreads();
        lds[tid] += t;
        __syncthreads();
    }
    if (tid < nb) partials[tid] = lds[tid] - v;  // exclusive
}

__global__ __launch_bounds__(256) void add_offsets_kernel(
    int* __restrict__ rowptr, const int* __restrict__ partials, int n) {
    int i = blockIdx.x * 256 + threadIdx.x;
    if (i < n) rowptr[i + 1] += partials[blockIdx.x];
    if (i == 0) rowptr[0] = 0;
}

__global__ void scatter_kernel(const int* __restrict__ src, const int* __restrict__ dst,
                               const int* __restrict__ rowptr, int* __restrict__ cnt,
                               int* __restrict__ src_sorted, int E) {
    int e = blockIdx.x * blockDim.x + threadIdx.x;
    if (e < E) {
        int d = dst[e];
        int p = rowptr[d] + atomicAdd(&cnt[d], 1);
        src_sorted[p] = src[e];
    }
}

// ---------------- GEMM: out[n, j] = sum_k X[n,k]*W[k,j] + b[j] ----------------
// Block: 256 threads, computes a 64(row) x 64(col) tile; per-thread 4x4.

template <int K>
__global__ __launch_bounds__(256) void gemm_bias_kernel(
    const float* __restrict__ X, const float* __restrict__ W,
    const float* __restrict__ bias, float* __restrict__ out,
    int nrows, int ncols) {
    // LDS budget: K=128 -> exactly 64KB (no padding); K=64 -> padded.
    constexpr int XP = (K == 128) ? 128 : (K + 1);
    constexpr int WP = (K == 128) ? 64  : 65;
    __shared__ float xs[64 * XP];
    __shared__ float ws[K * WP];

    int row0 = blockIdx.x * 64, col0 = blockIdx.y * 64;
    int tid = threadIdx.x;

    for (int idx = tid; idx < 64 * K; idx += 256) {
        int r = idx / K, c = idx % K;   // K is pow2 -> shifts
        int gr = row0 + r;
        xs[r * XP + c] = (gr < nrows) ? X[(size_t)gr * K + c] : 0.f;
    }
    for (int idx = tid; idx < K * 64; idx += 256) {
        int r = idx >> 6, c = idx & 63;
        ws[r * WP + c] = W[r * ncols + col0 + c];
    }
    __syncthreads();

    int tc = (tid & 15) * 4;
    int tr = (tid >> 4) * 4;
    float acc[4][4] = {};
    for (int k = 0; k < K; ++k) {
        float a[4], b[4];
        #pragma unroll
        for (int r = 0; r < 4; ++r) a[r] = xs[(tr + r) * XP + k];
        #pragma unroll
        for (int c = 0; c < 4; ++c) b[c] = ws[k * WP + tc + c];
        #pragma unroll
        for (int r = 0; r < 4; ++r)
            #pragma unroll
            for (int c = 0; c < 4; ++c) acc[r][c] += a[r] * b[c];
    }

    #pragma unroll
    for (int r = 0; r < 4; ++r) {
        int gr = row0 + tr + r;
        if (gr < nrows) {
            #pragma unroll
            for (int c = 0; c < 4; ++c)
                out[(size_t)gr * ncols + col0 + tc + c] = acc[r][c] + bias[col0 + tc + c];
        }
    }
}

// ---------------- Fused per-node online-softmax attention ----------------
// One wave (64 lanes) per destination node; lane = channel c in [0,64).
// H=2 heads held as paired registers.

__global__ __launch_bounds__(256) void attn_kernel(
    const float* __restrict__ Q, const float* __restrict__ Kb,
    const float* __restrict__ V, const float* __restrict__ S,
    const int* __restrict__ rowptr, const int* __restrict__ src_sorted,
    float* __restrict__ out, int n) {
    int wave = blockIdx.x * 4 + (threadIdx.x >> 6);
    int lane = threadIdx.x & 63;
    if (wave >= n) return;
    int node = wave;

    float q0 = Q[(size_t)node * 128 + lane];
    float q1 = Q[(size_t)node * 128 + 64 + lane];
    float m0 = -__builtin_inff(), m1 = -__builtin_inff();
    float s0 = 0.f, s1 = 0.f, a0 = 0.f, a1 = 0.f;

    int beg = rowptr[node], end = rowptr[node + 1];
    for (int i = beg; i < end; ++i) {
        int src = src_sorted[i];
        const float* kp = Kb + (size_t)src * 128;
        const float* vp = V + (size_t)src * 128;
        float k0 = kp[lane], k1 = kp[64 + lane];
        float v0 = vp[lane], v1 = vp[64 + lane];
        float d0 = q0 * k0, d1 = q1 * k1;
        #pragma unroll
        for (int off = 32; off >= 1; off >>= 1) {
            d0 += __shfl_xor(d0, off);
            d1 += __shfl_xor(d1, off);
        }
        d0 *= 0.125f;  // 1/sqrt(64)
        d1 *= 0.125f;
        float nm0 = fmaxf(m0, d0), nm1 = fmaxf(m1, d1);
        float f0 = __expf(m0 - nm0), f1 = __expf(m1 - nm1);
        float p0 = __expf(d0 - nm0), p1 = __expf(d1 - nm1);
        s0 = s0 * f0 + p0; a0 = a0 * f0 + p0 * v0; m0 = nm0;
        s1 = s1 * f1 + p1; a1 = a1 * f1 + p1 * v1; m1 = nm1;
    }

    float o = 0.5f * (a0 / (s0 + 1e-16f) + a1 / (s1 + 1e-16f));
    o += S[(size_t)node * 64 + lane];
    out[(size_t)node * 64 + lane] = fmaxf(o, 0.f);
}

// ---------------- launch ----------------

extern "C" void kernel_launch(void* const* d_in, const int* in_sizes, int n_in,
                              void* d_out, int out_size, void* d_ws, size_t ws_size,
                              hipStream_t stream) {
    const float* x = (const float*)d_in[0];
    const int* ei  = (const int*)d_in[1];
    const int N = in_sizes[0] / 128;
    const int E = in_sizes[1] / 2;
    const int* src = ei;
    const int* dst = ei + E;

    const float* Wq[3] = {(const float*)d_in[2],  (const float*)d_in[10], (const float*)d_in[18]};
    const float* bq[3] = {(const float*)d_in[3],  (const float*)d_in[11], (const float*)d_in[19]};
    const float* Wk[3] = {(const float*)d_in[4],  (const float*)d_in[12], (const float*)d_in[20]};
    const float* bk[3] = {(const float*)d_in[5],  (const float*)d_in[13], (const float*)d_in[21]};
    const float* Wv[3] = {(const float*)d_in[6],  (const float*)d_in[14], (const float*)d_in[22]};
    const float* bv[3] = {(const float*)d_in[7],  (const float*)d_in[15], (const float*)d_in[23]};
    const float* Wsk[3]= {(const float*)d_in[8],  (const float*)d_in[16], (const float*)d_in[24]};
    const float* bsk[3]= {(const float*)d_in[9],  (const float*)d_in[17], (const float*)d_in[25]};

    char* p = (char*)d_ws;
    int* rowptr = (int*)p; p += (size_t)(N + 1) * 4;
    int* cnt    = (int*)p; p += (size_t)N * 4;
    int* srcs   = (int*)p; p += (size_t)E * 4;
    int* partials = (int*)p; p += 256 * 4;
    p = (char*)(((uintptr_t)p + 255) & ~(uintptr_t)255);
    float* Qb = (float*)p; p += (size_t)N * 128 * 4;
    float* Kb = (float*)p; p += (size_t)N * 128 * 4;
    float* Vb = (float*)p; p += (size_t)N * 128 * 4;
    float* Sb = (float*)p; p += (size_t)N * 64 * 4;
    float* Hb = (float*)p; p += (size_t)N * 64 * 4;
    if ((size_t)(p - (char*)d_ws) > ws_size) return;  // workspace too small

    int nb = (N + 255) / 256;  // 196 <= 256
    hipMemsetAsync(cnt, 0, (size_t)N * 4, stream);
    hist_kernel<<<(E + 255) / 256, 256, 0, stream>>>(dst, cnt, E);
    block_scan_kernel<<<nb, 256, 0, stream>>>(cnt, rowptr, partials, N);
    partial_scan_kernel<<<1, 256, 0, stream>>>(partials, nb);
    add_offsets_kernel<<<nb, 256, 0, stream>>>(rowptr, partials, N);
    hipMemsetAsync(cnt, 0, (size_t)N * 4, stream);
    scatter_kernel<<<(E + 255) / 256, 256, 0, stream>>>(src, dst, rowptr, cnt, srcs, E);

    dim3 gq((N + 63) / 64, 2);   // 128-col outputs
    dim3 gs((N + 63) / 64, 1);   // 64-col output

    const float* X = x;
    for (int l = 0; l < 3; ++l) {
        if (l == 0) {
            gemm_bias_kernel<128><<<gq, 256, 0, stream>>>(X, Wq[l], bq[l], Qb, N, 128);
            gemm_bias_kernel<128><<<gq, 256, 0, stream>>>(X, Wk[l], bk[l], Kb, N, 128);
            gemm_bias_kernel<128><<<gq, 256, 0, stream>>>(X, Wv[l], bv[l], Vb, N, 128);
            gemm_bias_kernel<128><<<gs, 256, 0, stream>>>(X, Wsk[l], bsk[l], Sb, N, 64);
        } else {
            gemm_bias_kernel<64><<<gq, 256, 0, stream>>>(X, Wq[l], bq[l], Qb, N, 128);
            gemm_bias_kernel<64><<<gq, 256, 0, stream>>>(X, Wk[l], bk[l], Kb, N, 128);
            gemm_bias_kernel<64><<<gq, 256, 0, stream>>>(X, Wv[l], bv[l], Vb, N, 128);
            gemm_bias_kernel<64><<<gs, 256, 0, stream>>>(X, Wsk[l], bsk[l], Sb, N, 64);
        }
        float* outp = (l == 2) ? (float*)d_out : Hb;
        attn_kernel<<<(N + 3) / 4, 256, 0, stream>>>(Qb, Kb, Vb, Sb, rowptr, srcs, outp, N);
        X = Hb;
    }
}

// Round 3
// 521.225 us; speedup vs baseline: 2.2747x; 1.8904x over previous
//
#include <hip/hip_runtime.h>
#include <cstdint>

typedef _Float16 f16;
typedef __attribute__((ext_vector_type(2))) _Float16 f16x2;
typedef __attribute__((ext_vector_type(8))) _Float16 f16x8;
typedef __attribute__((ext_vector_type(4))) float f32x4;

// ---------------- CSR build ----------------

__global__ void hist_kernel(const int* __restrict__ dst, int* __restrict__ cnt, int E) {
    int e = blockIdx.x * blockDim.x + threadIdx.x;
    if (e < E) atomicAdd(&cnt[dst[e]], 1);
}

__global__ __launch_bounds__(256) void block_scan_kernel(
    const int* __restrict__ cnt, int* __restrict__ rowptr,
    int* __restrict__ partials, int n) {
    __shared__ int lds[256];
    int tid = threadIdx.x;
    int i = blockIdx.x * 256 + tid;
    int v = (i < n) ? cnt[i] : 0;
    lds[tid] = v;
    __syncthreads();
    for (int off = 1; off < 256; off <<= 1) {
        int t = (tid >= off) ? lds[tid - off] : 0;
        __syncthreads();
        lds[tid] += t;
        __syncthreads();
    }
    if (i < n) rowptr[i + 1] = lds[tid];
    if (tid == 255) partials[blockIdx.x] = lds[255];
}

__global__ __launch_bounds__(256) void partial_scan_kernel(int* __restrict__ partials, int nb) {
    __shared__ int lds[256];
    int tid = threadIdx.x;
    int v = (tid < nb) ? partials[tid] : 0;
    lds[tid] = v;
    __syncthreads();
    for (int off = 1; off < 256; off <<= 1) {
        int t = (tid >= off) ? lds[tid - off] : 0;
        __syncthreads();
        lds[tid] += t;
        __syncthreads();
    }
    if (tid < nb) partials[tid] = lds[tid] - v;  // exclusive
}

__global__ __launch_bounds__(256) void add_offsets_kernel(
    int* __restrict__ rowptr, const int* __restrict__ partials, int n) {
    int i = blockIdx.x * 256 + threadIdx.x;
    if (i < n) rowptr[i + 1] += partials[blockIdx.x];
    if (i == 0) rowptr[0] = 0;
}

__global__ void scatter_kernel(const int* __restrict__ src, const int* __restrict__ dst,
                               const int* __restrict__ rowptr, int* __restrict__ cnt,
                               int* __restrict__ src_sorted, int E) {
    int e = blockIdx.x * blockDim.x + threadIdx.x;
    if (e < E) {
        int d = dst[e];
        int p = rowptr[d] + atomicAdd(&cnt[d], 1);
        src_sorted[p] = src[e];
    }
}

// ---------------- fp32 -> fp16 convert (layer-1 input) ----------------

__global__ __launch_bounds__(256) void cvt_kernel(const float* __restrict__ in,
                                                  f16* __restrict__ out, int n8) {
    int i = blockIdx.x * 256 + threadIdx.x;
    if (i >= n8) return;
    float4 a = ((const float4*)in)[2 * i];
    float4 b = ((const float4*)in)[2 * i + 1];
    f16x8 o = {(f16)a.x, (f16)a.y, (f16)a.z, (f16)a.w,
               (f16)b.x, (f16)b.y, (f16)b.z, (f16)b.w};
    *(f16x8*)(out + 8 * i) = o;
}

// ---------------- weight prep: Wt[c][k] = W[k][c] (fp16), fused q|k|v|s ----------------

__global__ __launch_bounds__(256) void prep_w_kernel(
    const float* __restrict__ Wq, const float* __restrict__ Wk,
    const float* __restrict__ Wv, const float* __restrict__ Ws,
    const float* __restrict__ bq, const float* __restrict__ bk,
    const float* __restrict__ bv, const float* __restrict__ bs,
    f16* __restrict__ Wt, float* __restrict__ bias, int K) {
    int idx = blockIdx.x * 256 + threadIdx.x;
    if (idx < 448) {
        bias[idx] = (idx < 128) ? bq[idx]
                  : (idx < 256) ? bk[idx - 128]
                  : (idx < 384) ? bv[idx - 256]
                  : bs[idx - 384];
    }
    if (idx >= 448 * K) return;
    int c = idx / K, k = idx - c * K;
    float v;
    if (c < 128)      v = Wq[k * 128 + c];
    else if (c < 256) v = Wk[k * 128 + (c - 128)];
    else if (c < 384) v = Wv[k * 128 + (c - 256)];
    else              v = Ws[k * 64 + (c - 384)];
    Wt[(size_t)c * K + k] = (f16)v;
}

// ---------------- fused MFMA GEMM: out[M][448] = X[M][K] @ W[K][448] + b ----------------
// Block: 256 threads / 4 waves; tile 64 rows x 64 cols; wave = 16 rows x 64 cols.
// 16x16x32 f16 MFMA; LDS tiles XOR-swizzled (byte ^= (row&7)<<4) to kill the
// 16-way bank conflict of 256B/128B row strides on ds_read_b128.

template <int K>
__global__ __launch_bounds__(256) void gemm_qkvs_kernel(
    const f16* __restrict__ X, const f16* __restrict__ Wt,
    const float* __restrict__ bias, f16* __restrict__ out, int M) {
    __shared__ f16 xa[64 * K];
    __shared__ f16 wb[64 * K];
    constexpr int CPR = K / 8;  // 16B chunks per row
    int row0 = blockIdx.x * 64, col0 = blockIdx.y * 64;
    int tid = threadIdx.x;

    for (int c = tid; c < 64 * CPR; c += 256) {
        int r = c / CPR, kc = c % CPR;
        int gr = row0 + r;
        uint4 v = {0, 0, 0, 0};
        if (gr < M) v = *(const uint4*)(X + (size_t)gr * K + kc * 8);
        int off = (r * K + kc * 8) * 2;
        off ^= (r & 7) << 4;
        *(uint4*)((char*)xa + off) = v;
    }
    for (int c = tid; c < 64 * CPR; c += 256) {
        int r = c / CPR, kc = c % CPR;
        uint4 v = *(const uint4*)(Wt + (size_t)(col0 + r) * K + kc * 8);
        int off = (r * K + kc * 8) * 2;
        off ^= (r & 7) << 4;
        *(uint4*)((char*)wb + off) = v;
    }
    __syncthreads();

    int lane = tid & 63, wid = tid >> 6;
    int fr = lane & 15, fk = lane >> 4;
    int arow = wid * 16 + fr;
    f32x4 acc[4] = {};

    for (int ks = 0; ks < K; ks += 32) {
        int aoff = (arow * K + ks + fk * 8) * 2;
        aoff ^= (arow & 7) << 4;
        f16x8 af = *(f16x8*)((char*)xa + aoff);
        #pragma unroll
        for (int ct = 0; ct < 4; ++ct) {
            int brow = ct * 16 + fr;
            int boff = (brow * K + ks + fk * 8) * 2;
            boff ^= (brow & 7) << 4;
            f16x8 bf = *(f16x8*)((char*)wb + boff);
            acc[ct] = __builtin_amdgcn_mfma_f32_16x16x32_f16(af, bf, acc[ct], 0, 0, 0);
        }
    }

    // D layout: row = (lane>>4)*4 + reg (A's m), col = lane&15 (B's n)
    int orow = row0 + wid * 16 + fk * 4;
    int ocol = col0 + fr;
    #pragma unroll
    for (int ct = 0; ct < 4; ++ct) {
        float b = bias[ocol + ct * 16];
        #pragma unroll
        for (int r = 0; r < 4; ++r) {
            int gr = orow + r;
            if (gr < M) out[(size_t)gr * 448 + ocol + ct * 16] = (f16)(acc[ct][r] + b);
        }
    }
}

// ---------------- fused per-node online-softmax attention ----------------
// One wave per node. lane -> (head = lane>>5, channels 2*(lane&31), +1), i.e.
// col = 2*lane in the 128-wide q/k/v blocks. Dot reduce = 5 shfl_xor within
// the 32-lane half; head-mean = one shfl_xor(,32) at the end.

__global__ __launch_bounds__(256) void attn_kernel(
    const f16* __restrict__ T,  // [N][448] : q|k|v|s
    const int* __restrict__ rowptr, const int* __restrict__ srcs,
    f16* __restrict__ hout, float* __restrict__ fout, int n, int final_layer) {
    int node = blockIdx.x * 4 + (threadIdx.x >> 6);
    if (node >= n) return;
    int lane = threadIdx.x & 63;
    const size_t base = (size_t)node * 448;

    f16x2 qh = *(const f16x2*)(T + base + 2 * lane);
    float qx = qh[0], qy = qh[1];
    float m = -__builtin_inff(), s = 0.f, ax = 0.f, ay = 0.f;

    int beg = rowptr[node], end = rowptr[node + 1];
    for (int i = beg; i < end; ++i) {
        int sidx = srcs[i];
        const f16* p = T + (size_t)sidx * 448;
        f16x2 kh = *(const f16x2*)(p + 128 + 2 * lane);
        f16x2 vh = *(const f16x2*)(p + 256 + 2 * lane);
        float d = qx * (float)kh[0] + qy * (float)kh[1];
        d += __shfl_xor(d, 1);
        d += __shfl_xor(d, 2);
        d += __shfl_xor(d, 4);
        d += __shfl_xor(d, 8);
        d += __shfl_xor(d, 16);
        d *= 0.125f;  // 1/sqrt(64)
        float nm = fmaxf(m, d);
        float f  = __expf(m - nm);
        float pe = __expf(d - nm);
        s  = s * f + pe;
        ax = ax * f + pe * (float)vh[0];
        ay = ay * f + pe * (float)vh[1];
        m = nm;
    }

    float inv = 1.0f / (s + 1e-16f);
    float rx = ax * inv, ry = ay * inv;
    float ox = 0.5f * (rx + __shfl_xor(rx, 32));
    float oy = 0.5f * (ry + __shfl_xor(ry, 32));

    if (lane < 32) {
        f16x2 sk = *(const f16x2*)(T + base + 384 + 2 * lane);
        ox = fmaxf(ox + (float)sk[0], 0.f);
        oy = fmaxf(oy + (float)sk[1], 0.f);
        if (final_layer) {
            *(float2*)(fout + (size_t)node * 64 + 2 * lane) = make_float2(ox, oy);
        } else {
            f16x2 o = {(f16)ox, (f16)oy};
            *(f16x2*)(hout + (size_t)node * 64 + 2 * lane) = o;
        }
    }
}

// ---------------- launch ----------------

extern "C" void kernel_launch(void* const* d_in, const int* in_sizes, int n_in,
                              void* d_out, int out_size, void* d_ws, size_t ws_size,
                              hipStream_t stream) {
    const float* x = (const float*)d_in[0];
    const int* ei  = (const int*)d_in[1];
    const int N = in_sizes[0] / 128;
    const int E = in_sizes[1] / 2;
    const int* src = ei;
    const int* dst = ei + E;

    const float* Wq[3] = {(const float*)d_in[2],  (const float*)d_in[10], (const float*)d_in[18]};
    const float* bq[3] = {(const float*)d_in[3],  (const float*)d_in[11], (const float*)d_in[19]};
    const float* Wk[3] = {(const float*)d_in[4],  (const float*)d_in[12], (const float*)d_in[20]};
    const float* bk[3] = {(const float*)d_in[5],  (const float*)d_in[13], (const float*)d_in[21]};
    const float* Wv[3] = {(const float*)d_in[6],  (const float*)d_in[14], (const float*)d_in[22]};
    const float* bv[3] = {(const float*)d_in[7],  (const float*)d_in[15], (const float*)d_in[23]};
    const float* Wsk[3]= {(const float*)d_in[8],  (const float*)d_in[16], (const float*)d_in[24]};
    const float* bsk[3]= {(const float*)d_in[9],  (const float*)d_in[17], (const float*)d_in[25]};

    char* p = (char*)d_ws;
    int* rowptr   = (int*)p; p += (size_t)(N + 1) * 4;
    int* cnt      = (int*)p; p += (size_t)N * 4;
    int* srcs     = (int*)p; p += (size_t)E * 4;
    int* partials = (int*)p; p += 256 * 4;
    p = (char*)(((uintptr_t)p + 255) & ~(uintptr_t)255);
    f16* X16  = (f16*)p; p += (size_t)N * 128 * 2;
    f16* Xh   = (f16*)p; p += (size_t)N * 64 * 2;
    f16* QKVS = (f16*)p; p += (size_t)N * 448 * 2;
    f16* Wt   = (f16*)p; p += (size_t)448 * 128 * 2;
    float* bias = (float*)p; p += 448 * 4;
    if ((size_t)(p - (char*)d_ws) > ws_size) return;

    int nb = (N + 255) / 256;
    hipMemsetAsync(cnt, 0, (size_t)N * 4, stream);
    hist_kernel<<<(E + 255) / 256, 256, 0, stream>>>(dst, cnt, E);
    block_scan_kernel<<<nb, 256, 0, stream>>>(cnt, rowptr, partials, N);
    partial_scan_kernel<<<1, 256, 0, stream>>>(partials, nb);
    add_offsets_kernel<<<nb, 256, 0, stream>>>(rowptr, partials, N);
    hipMemsetAsync(cnt, 0, (size_t)N * 4, stream);
    scatter_kernel<<<(E + 255) / 256, 256, 0, stream>>>(src, dst, rowptr, cnt, srcs, E);

    cvt_kernel<<<(N * 128 / 8 + 255) / 256, 256, 0, stream>>>(x, X16, N * 128 / 8);

    int gx = (N + 63) / 64;
    for (int l = 0; l < 3; ++l) {
        int K = (l == 0) ? 128 : 64;
        prep_w_kernel<<<(448 * K + 255) / 256, 256, 0, stream>>>(
            Wq[l], Wk[l], Wv[l], Wsk[l], bq[l], bk[l], bv[l], bsk[l], Wt, bias, K);
        if (l == 0)
            gemm_qkvs_kernel<128><<<dim3(gx, 7), 256, 0, stream>>>(X16, Wt, bias, QKVS, N);
        else
            gemm_qkvs_kernel<64><<<dim3(gx, 7), 256, 0, stream>>>(Xh, Wt, bias, QKVS, N);
        attn_kernel<<<(N + 3) / 4, 256, 0, stream>>>(
            QKVS, rowptr, srcs, Xh, (float*)d_out, N, (l == 2) ? 1 : 0);
    }
}

// Round 4
// 373.223 us; speedup vs baseline: 3.1768x; 1.3965x over previous
//
#include <hip/hip_runtime.h>
#include <cstdint>

typedef _Float16 f16;
typedef __attribute__((ext_vector_type(2))) _Float16 f16x2;
typedef __attribute__((ext_vector_type(8))) _Float16 f16x8;
typedef __attribute__((ext_vector_type(4))) float f32x4;

// ---------------- CSR build ----------------

__global__ void hist_kernel(const int* __restrict__ dst, int* __restrict__ cnt, int E) {
    int e = blockIdx.x * blockDim.x + threadIdx.x;
    if (e < E) atomicAdd(&cnt[dst[e]], 1);
}

__global__ __launch_bounds__(256) void block_scan_kernel(
    const int* __restrict__ cnt, int* __restrict__ rowptr,
    int* __restrict__ partials, int n) {
    __shared__ int lds[256];
    int tid = threadIdx.x;
    int i = blockIdx.x * 256 + tid;
    int v = (i < n) ? cnt[i] : 0;
    lds[tid] = v;
    __syncthreads();
    for (int off = 1; off < 256; off <<= 1) {
        int t = (tid >= off) ? lds[tid - off] : 0;
        __syncthreads();
        lds[tid] += t;
        __syncthreads();
    }
    if (i < n) rowptr[i + 1] = lds[tid];
    if (tid == 255) partials[blockIdx.x] = lds[255];
}

__global__ __launch_bounds__(256) void partial_scan_kernel(int* __restrict__ partials, int nb) {
    __shared__ int lds[256];
    int tid = threadIdx.x;
    int v = (tid < nb) ? partials[tid] : 0;
    lds[tid] = v;
    __syncthreads();
    for (int off = 1; off < 256; off <<= 1) {
        int t = (tid >= off) ? lds[tid - off] : 0;
        __syncthreads();
        lds[tid] += t;
        __syncthreads();
    }
    if (tid < nb) partials[tid] = lds[tid] - v;  // exclusive
}

__global__ __launch_bounds__(256) void add_offsets_kernel(
    int* __restrict__ rowptr, const int* __restrict__ partials, int n) {
    int i = blockIdx.x * 256 + threadIdx.x;
    if (i < n) rowptr[i + 1] += partials[blockIdx.x];
    if (i == 0) rowptr[0] = 0;
}

__global__ void scatter_kernel(const int* __restrict__ src, const int* __restrict__ dst,
                               const int* __restrict__ rowptr, int* __restrict__ cnt,
                               int* __restrict__ src_sorted, int E) {
    int e = blockIdx.x * blockDim.x + threadIdx.x;
    if (e < E) {
        int d = dst[e];
        int p = rowptr[d] + atomicAdd(&cnt[d], 1);
        src_sorted[p] = src[e];
    }
}

// ---------------- fp32 -> fp16 convert (layer-1 input) ----------------

__global__ __launch_bounds__(256) void cvt_kernel(const float* __restrict__ in,
                                                  f16* __restrict__ out, int n8) {
    int i = blockIdx.x * 256 + threadIdx.x;
    if (i >= n8) return;
    float4 a = ((const float4*)in)[2 * i];
    float4 b = ((const float4*)in)[2 * i + 1];
    f16x8 o = {(f16)a.x, (f16)a.y, (f16)a.z, (f16)a.w,
               (f16)b.x, (f16)b.y, (f16)b.z, (f16)b.w};
    *(f16x8*)(out + 8 * i) = o;
}

// ---------------- weight prep: Wt[c][k] = W[k][c] (fp16), fused q|k|v|s ----------------

__global__ __launch_bounds__(256) void prep_w_kernel(
    const float* __restrict__ Wq, const float* __restrict__ Wk,
    const float* __restrict__ Wv, const float* __restrict__ Ws,
    const float* __restrict__ bq, const float* __restrict__ bk,
    const float* __restrict__ bv, const float* __restrict__ bs,
    f16* __restrict__ Wt, float* __restrict__ bias, int K) {
    int idx = blockIdx.x * 256 + threadIdx.x;
    if (idx < 448) {
        bias[idx] = (idx < 128) ? bq[idx]
                  : (idx < 256) ? bk[idx - 128]
                  : (idx < 384) ? bv[idx - 256]
                  : bs[idx - 384];
    }
    if (idx >= 448 * K) return;
    int c = idx / K, k = idx - c * K;
    float v;
    if (c < 128)      v = Wq[k * 128 + c];
    else if (c < 256) v = Wk[k * 128 + (c - 128)];
    else if (c < 384) v = Wv[k * 128 + (c - 256)];
    else              v = Ws[k * 64 + (c - 384)];
    Wt[(size_t)c * K + k] = (f16)v;
}

// ---------------- fused MFMA GEMM: out[M][448] = X[M][K] @ W[K][448] + b ----------------

template <int K>
__global__ __launch_bounds__(256) void gemm_qkvs_kernel(
    const f16* __restrict__ X, const f16* __restrict__ Wt,
    const float* __restrict__ bias, f16* __restrict__ out, int M) {
    __shared__ f16 xa[64 * K];
    __shared__ f16 wb[64 * K];
    constexpr int CPR = K / 8;  // 16B chunks per row
    int row0 = blockIdx.x * 64, col0 = blockIdx.y * 64;
    int tid = threadIdx.x;

    for (int c = tid; c < 64 * CPR; c += 256) {
        int r = c / CPR, kc = c % CPR;
        int gr = row0 + r;
        uint4 v = {0, 0, 0, 0};
        if (gr < M) v = *(const uint4*)(X + (size_t)gr * K + kc * 8);
        int off = (r * K + kc * 8) * 2;
        off ^= (r & 7) << 4;
        *(uint4*)((char*)xa + off) = v;
    }
    for (int c = tid; c < 64 * CPR; c += 256) {
        int r = c / CPR, kc = c % CPR;
        uint4 v = *(const uint4*)(Wt + (size_t)(col0 + r) * K + kc * 8);
        int off = (r * K + kc * 8) * 2;
        off ^= (r & 7) << 4;
        *(uint4*)((char*)wb + off) = v;
    }
    __syncthreads();

    int lane = tid & 63, wid = tid >> 6;
    int fr = lane & 15, fk = lane >> 4;
    int arow = wid * 16 + fr;
    f32x4 acc[4] = {};

    for (int ks = 0; ks < K; ks += 32) {
        int aoff = (arow * K + ks + fk * 8) * 2;
        aoff ^= (arow & 7) << 4;
        f16x8 af = *(f16x8*)((char*)xa + aoff);
        #pragma unroll
        for (int ct = 0; ct < 4; ++ct) {
            int brow = ct * 16 + fr;
            int boff = (brow * K + ks + fk * 8) * 2;
            boff ^= (brow & 7) << 4;
            f16x8 bf = *(f16x8*)((char*)wb + boff);
            acc[ct] = __builtin_amdgcn_mfma_f32_16x16x32_f16(af, bf, acc[ct], 0, 0, 0);
        }
    }

    int orow = row0 + wid * 16 + fk * 4;
    int ocol = col0 + fr;
    #pragma unroll
    for (int ct = 0; ct < 4; ++ct) {
        float b = bias[ocol + ct * 16];
        #pragma unroll
        for (int r = 0; r < 4; ++r) {
            int gr = orow + r;
            if (gr < M) out[(size_t)gr * 448 + ocol + ct * 16] = (f16)(acc[ct][r] + b);
        }
    }
}

// ---------------- fused per-node online-softmax attention ----------------
// One wave per node; lane = (e2:bits4-5, h:bit3, c8:bits0-2).
// 4 edges per iteration; each lane owns an 8-channel f16x8 slice (16B loads).
// Dot reduce: 3 shfls over c8 (shared by 4 edges); tile max: 2 shfls over e2.
// s and the V-accumulator stay per-lane partials, reduced over e2 post-loop.

__global__ __launch_bounds__(256) void attn_kernel(
    const f16* __restrict__ T,  // [N][448] : q|k|v|s
    const int* __restrict__ rowptr, const int* __restrict__ srcs,
    f16* __restrict__ hout, float* __restrict__ fout, int n, int final_layer) {
    int node = blockIdx.x * 4 + (threadIdx.x >> 6);
    if (node >= n) return;
    int lane = threadIdx.x & 63;
    int c8 = lane & 7, h = (lane >> 3) & 1, e2 = lane >> 4;
    const size_t base = (size_t)node * 448;
    const int coff = h * 64 + c8 * 8;

    f16x8 q = *(const f16x8*)(T + base + coff);
    float m = -__builtin_inff(), s = 0.f;
    float av[8] = {};

    int beg = rowptr[node], end = rowptr[node + 1];
    for (int i0 = beg; i0 < end; i0 += 4) {
        int i = i0 + e2;
        bool valid = (i < end);
        int sidx = srcs[valid ? i : (end - 1)];
        const f16* p = T + (size_t)sidx * 448 + coff;
        f16x8 kv = *(const f16x8*)(p + 128);
        f16x8 vv = *(const f16x8*)(p + 256);
        float d = 0.f;
        #pragma unroll
        for (int j = 0; j < 8; ++j) d += (float)q[j] * (float)kv[j];
        d += __shfl_xor(d, 1);
        d += __shfl_xor(d, 2);
        d += __shfl_xor(d, 4);
        d *= 0.125f;  // 1/sqrt(64)
        if (!valid) d = -__builtin_inff();
        float dmax = fmaxf(d, __shfl_xor(d, 16));
        dmax = fmaxf(dmax, __shfl_xor(dmax, 32));
        float nm = fmaxf(m, dmax);
        float f  = __expf(m - nm);
        float pe = __expf(d - nm);
        s = s * f + pe;
        #pragma unroll
        for (int j = 0; j < 8; ++j) av[j] = av[j] * f + pe * (float)vv[j];
        m = nm;
    }

    // reduce partials over the 4 edge-groups (lane bits 4-5)
    s += __shfl_xor(s, 16);
    s += __shfl_xor(s, 32);
    float inv = 1.0f / (s + 1e-16f);
    float r[8];
    #pragma unroll
    for (int j = 0; j < 8; ++j) {
        float a = av[j];
        a += __shfl_xor(a, 16);
        a += __shfl_xor(a, 32);
        r[j] = a * inv;
    }
    // head mean: combine h=0 (bit3=0) with h=1
    #pragma unroll
    for (int j = 0; j < 8; ++j) r[j] = 0.5f * (r[j] + __shfl_xor(r[j], 8));

    if (lane < 8) {  // e2==0, h==0: 8 lanes x 8 channels = 64 outputs
        f16x8 sk = *(const f16x8*)(T + base + 384 + c8 * 8);
        #pragma unroll
        for (int j = 0; j < 8; ++j) r[j] = fmaxf(r[j] + (float)sk[j], 0.f);
        if (final_layer) {
            float4 o0 = make_float4(r[0], r[1], r[2], r[3]);
            float4 o1 = make_float4(r[4], r[5], r[6], r[7]);
            float4* dst4 = (float4*)(fout + (size_t)node * 64 + c8 * 8);
            dst4[0] = o0;
            dst4[1] = o1;
        } else {
            f16x8 o = {(f16)r[0], (f16)r[1], (f16)r[2], (f16)r[3],
                       (f16)r[4], (f16)r[5], (f16)r[6], (f16)r[7]};
            *(f16x8*)(hout + (size_t)node * 64 + c8 * 8) = o;
        }
    }
}

// ---------------- launch ----------------

extern "C" void kernel_launch(void* const* d_in, const int* in_sizes, int n_in,
                              void* d_out, int out_size, void* d_ws, size_t ws_size,
                              hipStream_t stream) {
    const float* x = (const float*)d_in[0];
    const int* ei  = (const int*)d_in[1];
    const int N = in_sizes[0] / 128;
    const int E = in_sizes[1] / 2;
    const int* src = ei;
    const int* dst = ei + E;

    const float* Wq[3] = {(const float*)d_in[2],  (const float*)d_in[10], (const float*)d_in[18]};
    const float* bq[3] = {(const float*)d_in[3],  (const float*)d_in[11], (const float*)d_in[19]};
    const float* Wk[3] = {(const float*)d_in[4],  (const float*)d_in[12], (const float*)d_in[20]};
    const float* bk[3] = {(const float*)d_in[5],  (const float*)d_in[13], (const float*)d_in[21]};
    const float* Wv[3] = {(const float*)d_in[6],  (const float*)d_in[14], (const float*)d_in[22]};
    const float* bv[3] = {(const float*)d_in[7],  (const float*)d_in[15], (const float*)d_in[23]};
    const float* Wsk[3]= {(const float*)d_in[8],  (const float*)d_in[16], (const float*)d_in[24]};
    const float* bsk[3]= {(const float*)d_in[9],  (const float*)d_in[17], (const float*)d_in[25]};

    char* p = (char*)d_ws;
    int* rowptr   = (int*)p; p += (size_t)(N + 1) * 4;
    int* cnt      = (int*)p; p += (size_t)N * 4;
    int* srcs     = (int*)p; p += (size_t)E * 4;
    int* partials = (int*)p; p += 256 * 4;
    p = (char*)(((uintptr_t)p + 255) & ~(uintptr_t)255);
    f16* X16  = (f16*)p; p += (size_t)N * 128 * 2;
    f16* Xh   = (f16*)p; p += (size_t)N * 64 * 2;
    f16* QKVS = (f16*)p; p += (size_t)N * 448 * 2;
    f16* Wt   = (f16*)p; p += (size_t)448 * 128 * 2;
    float* bias = (float*)p; p += 448 * 4;
    if ((size_t)(p - (char*)d_ws) > ws_size) return;

    int nb = (N + 255) / 256;
    hipMemsetAsync(cnt, 0, (size_t)N * 4, stream);
    hist_kernel<<<(E + 255) / 256, 256, 0, stream>>>(dst, cnt, E);
    block_scan_kernel<<<nb, 256, 0, stream>>>(cnt, rowptr, partials, N);
    partial_scan_kernel<<<1, 256, 0, stream>>>(partials, nb);
    add_offsets_kernel<<<nb, 256, 0, stream>>>(rowptr, partials, N);
    hipMemsetAsync(cnt, 0, (size_t)N * 4, stream);
    scatter_kernel<<<(E + 255) / 256, 256, 0, stream>>>(src, dst, rowptr, cnt, srcs, E);

    cvt_kernel<<<(N * 128 / 8 + 255) / 256, 256, 0, stream>>>(x, X16, N * 128 / 8);

    int gx = (N + 63) / 64;
    for (int l = 0; l < 3; ++l) {
        int K = (l == 0) ? 128 : 64;
        prep_w_kernel<<<(448 * K + 255) / 256, 256, 0, stream>>>(
            Wq[l], Wk[l], Wv[l], Wsk[l], bq[l], bk[l], bv[l], bsk[l], Wt, bias, K);
        if (l == 0)
            gemm_qkvs_kernel<128><<<dim3(gx, 7), 256, 0, stream>>>(X16, Wt, bias, QKVS, N);
        else
            gemm_qkvs_kernel<64><<<dim3(gx, 7), 256, 0, stream>>>(Xh, Wt, bias, QKVS, N);
        attn_kernel<<<(N + 3) / 4, 256, 0, stream>>>(
            QKVS, rowptr, srcs, Xh, (float*)d_out, N, (l == 2) ? 1 : 0);
    }
}